// Round 1
// baseline (386.561 us; speedup 1.0000x reference)
//
#include <hip/hip_runtime.h>

// Recurrent ALIF 2D layer, forward only.
// x: (B=8, T=64, H=16, W=16, F=256) f32, w_rec: (256,256) f32.
// Key facts:
//  - Sites (b,h,w) are independent: recurrence couples only the feature dim.
//  - prev_s is exactly {0,1}: rec_input = sum of active rows of w_rec.
//    Summing active rows in increasing k is bit-identical to a sequential-k
//    fp32 FMA GEMM (fma by 0/1 is exact), minimizing divergence vs XLA.
// Design: one block (256 threads) per site; thread = feature; T-loop in-kernel.
// Per step: ballot-compact active spike indices into LDS (sorted), then each
// thread gathers W[k][f] (coalesced 1KiB rows, L2-resident) and accumulates.

#define FDIM 256
#define TSTEPS 64
#define HWDIM 256  // H*W = 16*16

__global__ __launch_bounds__(256, 8) void alif_kernel(
    const float* __restrict__ x,
    const float* __restrict__ w_rec,
    const float* __restrict__ hp_d_p,
    const float* __restrict__ hp_adp_p,
    const float* __restrict__ hp_beta_p,
    float* __restrict__ out)
{
    const int tid  = threadIdx.x;   // feature index f
    const int blk  = blockIdx.x;    // site index: b*HW + hw
    const int wave = tid >> 6;
    const int lane = tid & 63;

    const float d    = hp_d_p[0];
    const float adp  = hp_adp_p[0];
    const float beta = hp_beta_p[0];

    __shared__ int list[FDIM];                 // compacted active k indices
    __shared__ unsigned long long wmask[4];    // per-wave ballot masks

    const int b  = blk >> 8;
    const int hw = blk & 255;
    // flat index of x[b, t=0, hw, f]; layout (B, T, H, W, F)
    size_t idx = (size_t)b * TSTEPS * (HWDIM * FDIM) + (size_t)hw * FDIM + tid;
    const size_t tstride = (size_t)HWDIM * FDIM;  // 65536

    const float* wcol = w_rec + tid;  // column f of W (row-major W[k][f])

    float v = 0.f, th = 0.f, s = 0.f;

    for (int t = 0; t < TSTEPS; ++t) {
        float xt = x[idx];  // coalesced, issued early

        // ---- compact active spike indices, increasing-k order ----
        unsigned long long m = __ballot(s != 0.f);
        if (lane == 0) wmask[wave] = m;
        __syncthreads();
        int base = 0, total = 0;
        #pragma unroll
        for (int w = 0; w < 4; ++w) {
            int c = __popcll(wmask[w]);
            if (w < wave) base += c;
            total += c;
        }
        if (s != 0.f) {
            int pos = base + __popcll(m & ((1ull << lane) - 1ull));
            list[pos] = tid;
        }
        __syncthreads();

        // ---- rec_f = sum over active k (increasing k) of W[k][f] ----
        float rec = 0.f;
        for (int i = 0; i < total; ++i) {
            int k = list[i];                    // LDS broadcast read
            rec += wcol[(size_t)k << 8];        // coalesced across threads
        }

        // ---- elementwise ALIF update ----
        th = fmaf(th, adp, s * beta);           // theta*adp + prev_s*beta (s*beta exact)
        float vn  = fmaf(v, d, xt) + rec;       // v*d + x_t + rec
        float vth = 0.5f + th;
        float sn  = (vn - vth) > 0.f ? 1.f : 0.f;
        v = vn - sn * vth;                      // subtract exactly when spiked
        s = sn;
        out[idx] = sn;

        idx += tstride;
        __syncthreads();  // protect wmask/list from next iteration's writes
    }
}

extern "C" void kernel_launch(void* const* d_in, const int* in_sizes, int n_in,
                              void* d_out, int out_size, void* d_ws, size_t ws_size,
                              hipStream_t stream) {
    const float* x     = (const float*)d_in[0];
    const float* w_rec = (const float*)d_in[1];
    const float* hp_d  = (const float*)d_in[2];
    const float* hp_adp  = (const float*)d_in[3];
    const float* hp_beta = (const float*)d_in[4];
    // d_in[5] = hp_alpha: unused in forward
    float* out = (float*)d_out;

    // 2048 sites (8*16*16), one block each = 8 blocks/CU on 256 CUs.
    alif_kernel<<<2048, 256, 0, stream>>>(x, w_rec, hp_d, hp_adp, hp_beta, out);
}